// Round 16
// baseline (627.331 us; speedup 1.0000x reference)
//
#include <hip/hip_runtime.h>
#include <math.h>

typedef unsigned short u16;
typedef __attribute__((ext_vector_type(4))) unsigned short u16x4;
typedef __attribute__((ext_vector_type(8))) short s16x8;
typedef __attribute__((ext_vector_type(4))) float f32x4;
typedef __attribute__((ext_vector_type(4))) float f4v;

#define DEVI static __device__ __forceinline__

DEVI u16 f2bf(float f) {
  union { float f; unsigned u; } c; c.f = f;
  return (u16)((c.u + 0x7FFFu + ((c.u >> 16) & 1u)) >> 16);
}
DEVI float bf2f(u16 h) {
  union { unsigned u; float f; } c; c.u = ((unsigned)h) << 16;
  return c.f;
}
DEVI unsigned cvt_pk_bf16(float lo, float hi) {  // [15:0]=bf16(lo),[31:16]=bf16(hi), RNE
  unsigned r;
  asm("v_cvt_pk_bf16_f32 %0, %1, %2" : "=v"(r) : "v"(lo), "v"(hi));
  return r;
}

DEVI float tanh_fast(float x) {          // branch-free: 1-2/(e^{2x}+1)
  float e = __expf(2.0f * x);
  float r = __builtin_amdgcn_rcpf(e + 1.0f);
  return fmaf(-2.0f, r, 1.0f);
}
DEVI float gelu_fast(float x) {          // tanh-form gelu
  float x2 = x * x;
  float u = x * fmaf(x2, 0.0356774081f, 0.7978845608f);
  float e = __expf(2.0f * u);
  float r = __builtin_amdgcn_rcpf(e + 1.0f);
  float t = fmaf(-2.0f, r, 1.0f);
  float hx = 0.5f * x;
  return fmaf(hx, t, hx);
}

DEVI void load_lds16(const u16* g, u16* l) {
  __builtin_amdgcn_global_load_lds(
      (const __attribute__((address_space(1))) void*)g,
      (__attribute__((address_space(3))) void*)l, 16, 0, 0);
}

// phase-head sync: counted vmcnt (retire the 2-phases-old stage group) + barrier
#define SYNC_VM3() asm volatile("s_waitcnt vmcnt(3)\n\ts_barrier" ::: "memory")
#define SYNC_VM0() asm volatile("s_waitcnt vmcnt(0)\n\ts_barrier" ::: "memory")
// ds_read drain before MFMA burst (rule 18: lgkm + sched fence)
#define LGKM0()                                                \
  asm volatile("s_waitcnt lgkmcnt(0)" ::: "memory");           \
  __builtin_amdgcn_sched_barrier(0)

// ------------------------- small kernels -------------------------

__global__ __launch_bounds__(256) void cast3_kernel(
    const float* __restrict__ wd, const float* __restrict__ w1,
    const float* __restrict__ w2, u16* __restrict__ owd,
    u16* __restrict__ ow1, u16* __restrict__ ow2) {
  const int n1 = 262144, n2 = 1048576;  // in float4 units
  int i = blockIdx.x * 256 + threadIdx.x;
  const float* src; u16* dst; int j;
  if (i < n1) { src = wd; dst = owd; j = i; }
  else if (i < n1 + n2) { src = w1; dst = ow1; j = i - n1; }
  else { src = w2; dst = ow2; j = i - n1 - n2; }
  f4v f = ((const f4v*)src)[j];
  u16x4 o;
  o[0] = f2bf(f[0]); o[1] = f2bf(f[1]); o[2] = f2bf(f[2]); o[3] = f2bf(f[3]);
  ((u16x4*)dst)[j] = o;
}

__global__ __launch_bounds__(256) void prob_kernel(
    const float* __restrict__ q, const float* __restrict__ k,
    u16* __restrict__ A, u16* __restrict__ Bm) {
  const int D = 1024;
  size_t row = blockIdx.x;
  int t = threadIdx.x;
  f4v qv = ((const f4v*)(q + row * D))[t];
  f4v kv = ((const f4v*)(k + row * D))[t];
  float tq[4], tk[4];
  float sq = 0.f, sk = 0.f;
#pragma unroll
  for (int i = 0; i < 4; i++) {
    tq[i] = tanh_fast(qv[i]) * 0.499f + 0.5f;
    tk[i] = tanh_fast(kv[i]) * 0.499f + 0.5f;
    sq += tq[i]; sk += tk[i];
  }
#pragma unroll
  for (int off = 32; off > 0; off >>= 1) {
    sq += __shfl_xor(sq, off);
    sk += __shfl_xor(sk, off);
  }
  __shared__ float sbq[4], sbk[4];
  int lane = t & 63, w = t >> 6;
  if (lane == 0) { sbq[w] = sq; sbk[w] = sk; }
  __syncthreads();
  sq = sbq[0] + sbq[1] + sbq[2] + sbq[3];
  sk = sbk[0] + sbk[1] + sbk[2] + sbk[3];
  float iq = 1.0f / (sq + 1e-8f), ik = 1.0f / (sk + 1e-8f);
  u16x4 av, bv;
#pragma unroll
  for (int i = 0; i < 4; i++) {
    float qp = fmaxf(tq[i] * iq, 1e-8f);
    float kp = fmaxf(tk[i] * ik, 1e-8f);
    av[i] = f2bf(qp - kp);
    bv[i] = f2bf(__logf(qp) - __logf(kp));
  }
  ((u16x4*)(A + row * D))[t] = av;
  ((u16x4*)(Bm + row * D))[t] = bv;
}

__global__ __launch_bounds__(256) void transpose_v_kernel(
    const float* __restrict__ v, u16* __restrict__ Vt) {
  const int N = 2048, D = 1024;
  __shared__ float tile[32][33];
  int b = blockIdx.z;
  int d0 = blockIdx.x * 32, n0 = blockIdx.y * 32;
  int tx = threadIdx.x & 31, ty = threadIdx.x >> 5;
  const float* vb = v + (size_t)b * N * D;
  u16* vtb = Vt + (size_t)b * N * D;
#pragma unroll
  for (int i = 0; i < 4; i++)
    tile[ty + i * 8][tx] = vb[(size_t)(n0 + ty + i * 8) * D + d0 + tx];
  __syncthreads();
#pragma unroll
  for (int i = 0; i < 4; i++)
    vtb[(size_t)(d0 + ty + i * 8) * N + n0 + tx] = f2bf(tile[tx][ty + i * 8]);
}

__global__ __launch_bounds__(256) void softmax_rows_kernel(u16* __restrict__ S) {
  const int NN = 2048;
  size_t row = blockIdx.x;
  u16* r = S + row * NN;
  int t = threadIdx.x;
  s16x8 vv = ((const s16x8*)r)[t];
  float x[8];
  float mx = -1e30f;
#pragma unroll
  for (int i = 0; i < 8; i++) { x[i] = bf2f((u16)vv[i]); mx = fmaxf(mx, x[i]); }
#pragma unroll
  for (int off = 32; off > 0; off >>= 1) mx = fmaxf(mx, __shfl_xor(mx, off));
  __shared__ float sm[4], ss[4];
  int lane = t & 63, w = t >> 6;
  if (lane == 0) sm[w] = mx;
  __syncthreads();
  mx = fmaxf(fmaxf(sm[0], sm[1]), fmaxf(sm[2], sm[3]));
  float sum = 0.f;
#pragma unroll
  for (int i = 0; i < 8; i++) { x[i] = __expf(x[i] - mx); sum += x[i]; }
#pragma unroll
  for (int off = 32; off > 0; off >>= 1) sum += __shfl_xor(sum, off);
  if (lane == 0) ss[w] = sum;
  __syncthreads();
  float inv = 1.0f / (ss[0] + ss[1] + ss[2] + ss[3]);
  s16x8 ov;
#pragma unroll
  for (int i = 0; i < 8; i++) ov[i] = (short)f2bf(x[i] * inv);
  ((s16x8*)r)[t] = ov;
}

// LN rows of 1024. IN_BF16: input u16*, else f32*. OUT_BF16: out u16*, else f32*.
template <int IN_BF16, int OUT_BF16>
__global__ __launch_bounds__(256) void layernorm_rows_kernel(
    const void* __restrict__ inp, void* __restrict__ outp,
    const float* __restrict__ g, const float* __restrict__ bia) {
  const int D = 1024;
  size_t row = blockIdx.x;
  int t = threadIdx.x;
  f4v xv;
  if (IN_BF16) {
    u16x4 h4 = ((const u16x4*)inp)[row * (D / 4) + t];
    xv[0] = bf2f(h4[0]); xv[1] = bf2f(h4[1]); xv[2] = bf2f(h4[2]); xv[3] = bf2f(h4[3]);
  } else {
    xv = ((const f4v*)inp)[row * (D / 4) + t];
  }
  float s = xv[0] + xv[1] + xv[2] + xv[3];
  float s2 = xv[0] * xv[0] + xv[1] * xv[1] + xv[2] * xv[2] + xv[3] * xv[3];
#pragma unroll
  for (int off = 32; off > 0; off >>= 1) {
    s += __shfl_xor(s, off);
    s2 += __shfl_xor(s2, off);
  }
  __shared__ float sa[4], sb[4];
  int lane = t & 63, w = t >> 6;
  if (lane == 0) { sa[w] = s; sb[w] = s2; }
  __syncthreads();
  s = sa[0] + sa[1] + sa[2] + sa[3];
  s2 = sb[0] + sb[1] + sb[2] + sb[3];
  float mean = s * (1.0f / D);
  float var = s2 * (1.0f / D) - mean * mean;
  float rs = rsqrtf(var + 1e-5f);
  f4v gv = ((const f4v*)g)[t];
  f4v bv = ((const f4v*)bia)[t];
  float y[4];
#pragma unroll
  for (int i = 0; i < 4; i++) y[i] = (xv[i] - mean) * rs * gv[i] + bv[i];
  if (OUT_BF16) {
    u16x4 o; o[0] = f2bf(y[0]); o[1] = f2bf(y[1]); o[2] = f2bf(y[2]); o[3] = f2bf(y[3]);
    ((u16x4*)outp)[row * (D / 4) + t] = o;
  } else {
    f4v o; o[0] = y[0]; o[1] = y[1]; o[2] = y[2]; o[3] = y[3];
    ((f4v*)outp)[row * (D / 4) + t] = o;
  }
}

// ---------- 256x128 BK=32 NT GEMM, triple-buffered, 2 blocks/CU ----------
// Round-16 (= round-15 with the sB name collision fixed). Round-14's
// 2-slot/2-phase ledger raced (ds_read before the forcing vmcnt+barrier).
// Fix: 3 LDS slots (72 KB) and sync at PHASE HEAD, reads after the barrier:
//   phase p: {vmcnt(3)+barrier}  -> retires G_{p-2} (= tile p's stage,
//            issued 2 phases ago, HBM latency covered)
//            rd(slot p%3); stage tile p+2 -> slot (p+2)%3;
//            lgkmcnt(0)+sched_fence; 16 MFMA.
// Ledger: prologue stages tiles 0,1 (6 loads). Steady: 6 -> vm3 -> 3 ->
// stage -> 6. WAR: stage at p writes slot (p-1)%3 whose reads retired at
// p-1's LGKM0 before any wave reaches p's barrier. Tail: two phases with
// waits {3,0}, no stage.
// Occupancy: 8 waves as 4Mx2N, per-wave 64x64 (acc 64 VGPR), LDS 72 KB,
// __launch_bounds__(512,4) -> 2 blocks/CU: one block's MFMA hides the
// other's LDS/stage phase (m97/m114 mechanism).
// Swizzle (both-sides): read chunk = fq ^ ((row>>1)&3); stage source chunk
// = (t&3) ^ ((t>>3)&3); LDS dest linear t*16 B.
// Slot layout (bytes): slot*24576 + {A h0: 0, A h1: 8192, B: 16384}.
// EPI 0: C=bf16(acc*scale)  1: C=bf16(aux1-acc)  3: C=bf16(gelu(acc+aux2))
// 6: C=bf16(acc+aux2[col]+f32 aux1[ci])  7: C=bf16(acc+aux2[col]+bf16 aux1[ci])
template <int EPI>
__global__ __launch_bounds__(512, 4) void gemm8_kernel(
    const u16* __restrict__ Ab, const u16* __restrict__ Bb,
    void* __restrict__ Cout,
    const float* __restrict__ aux1, const float* __restrict__ aux2,
    int M, int Nc, int K,
    long sA, long sB, long sC, long sAux1, float scale) {
  __shared__ u16 lds[36864];  // 3 slots x 24576 B

  int nwg = gridDim.x;
  int orig = blockIdx.x;
  int swz = (orig & 7) * (nwg >> 3) + (orig >> 3);
  int gxm = M >> 8, gyn = Nc >> 7;
  int pb = gxm * gyn;
  int bz = swz / pb;
  int rem = swz - bz * pb;
  int gsz = gyn << 3;
  int gid = rem / gsz;
  int lr = rem - gid * gsz;
  int bx = (gid << 3) + (lr & 7);
  int by = lr >> 3;
  int m0 = bx << 8, n0 = by << 7;

  const u16* Ap = Ab + (size_t)bz * sA;
  const u16* Bp = Bb + (size_t)bz * sB;

  int t = threadIdx.x, wid = t >> 6, l = t & 63;
  int wr = wid >> 1, wc = wid & 1;
  int frow = l & 15, fq = l >> 4;

  // stage mapping: thread t -> within-half row t>>2, lds chunk t&3 (linear
  // dest t*16 B); source chunk inverse-swizzled.
  int srow = t >> 2;
  int scg = ((t & 3) ^ ((t >> 3) & 3)) * 8;
  const u16* pB  = Bp + ((size_t)n0 + srow) * K + scg;
  const u16* pA0 = Ap + ((size_t)m0 + srow) * K + scg;
  const u16* pA1 = pA0 + (size_t)128 * K;

  // read byte offsets within a slot (thread-invariant)
  int aoffs[4], boffs[4];
  int abase = (wr >> 1) * 8192;
#pragma unroll
  for (int m = 0; m < 4; m++) {
    int rh = (wr & 1) * 64 + m * 16 + frow;
    aoffs[m] = abase + rh * 64 + ((fq ^ ((rh >> 1) & 3)) * 16);
  }
#pragma unroll
  for (int n = 0; n < 4; n++) {
    int rb = wc * 64 + n * 16 + frow;
    boffs[n] = 16384 + rb * 64 + ((fq ^ ((rb >> 1) & 3)) * 16);
  }

  s16x8 af[4], bf[4];
  auto rdAB = [&](int slotB) {  // slotB = slot BYTE base
#pragma unroll
    for (int m = 0; m < 4; m++)
      af[m] = *(const s16x8*)((const char*)lds + (aoffs[m] + slotB));
#pragma unroll
    for (int n = 0; n < 4; n++)
      bf[n] = *(const s16x8*)((const char*)lds + (boffs[n] + slotB));
  };
  auto stage = [&](int slotU16, const u16* b, const u16* a0, const u16* a1) {
    load_lds16(b,  &lds[slotU16 + 8192 + t * 8]);
    load_lds16(a0, &lds[slotU16 + t * 8]);
    load_lds16(a1, &lds[slotU16 + 4096 + t * 8]);
  };

  f32x4 acc[4][4];
#pragma unroll
  for (int m = 0; m < 4; m++)
#pragma unroll
    for (int n = 0; n < 4; n++) acc[m][n] = (f32x4){0.f, 0.f, 0.f, 0.f};

#define MFMA_ALL()                                                            \
  do {                                                                        \
    __builtin_amdgcn_s_setprio(1);                                            \
    _Pragma("unroll") for (int m = 0; m < 4; m++)                             \
        _Pragma("unroll") for (int n = 0; n < 4; n++)                         \
            acc[m][n] = __builtin_amdgcn_mfma_f32_16x16x32_bf16(              \
                af[m], bf[n], acc[m][n], 0, 0, 0);                            \
    __builtin_amdgcn_s_setprio(0);                                            \
  } while (0)

  // prologue: stage tile0 -> slot0, tile1 -> slot1
  stage(0, pB, pA0, pA1);
  stage(12288, pB + 32, pA0 + 32, pA1 + 32);

  int nt = K >> 5;
  int cur = 0;        // slot u16 base of tile p
  int stg = 24576;    // slot u16 base of tile p+2
  const u16* gB  = pB + 64;
  const u16* gA0 = pA0 + 64;
  const u16* gA1 = pA1 + 64;
  for (int p = 0; p < nt - 2; p++) {
    SYNC_VM3();
    rdAB(cur * 2);               // byte base = u16 base * 2
    stage(stg, gB, gA0, gA1);
    LGKM0();
    MFMA_ALL();
    gB += 32; gA0 += 32; gA1 += 32;
    cur = (cur == 24576) ? 0 : cur + 12288;
    stg = (stg == 24576) ? 0 : stg + 12288;
  }
  // tail phase nt-2: retire G_{nt-4}; read; no stage
  SYNC_VM3();
  rdAB(cur * 2);
  LGKM0();
  MFMA_ALL();
  cur = (cur == 24576) ? 0 : cur + 12288;
  // tail phase nt-1: retire last group; read; done
  SYNC_VM0();
  rdAB(cur * 2);
  LGKM0();
  MFMA_ALL();
#undef MFMA_ALL

  // epilogue: row = m0 + wr*64 + m*16 + fq*4 + r; col = n0 + wc*64 + n*16 + frow
#pragma unroll
  for (int m = 0; m < 4; m++) {
#pragma unroll
    for (int n = 0; n < 4; n++) {
      f32x4 a4 = acc[m][n];
      int gcol = n0 + wc * 64 + n * 16 + frow;
#pragma unroll
      for (int rp = 0; rp < 2; rp++) {
        int grow0 = m0 + wr * 64 + m * 16 + fq * 4 + rp * 2;
        size_t ci0 = (size_t)grow0 * Nc + gcol;
        if (EPI == 0) {
          unsigned pk = cvt_pk_bf16(a4[rp * 2] * scale, a4[rp * 2 + 1] * scale);
          ((u16*)Cout)[(size_t)bz * sC + ci0] = (u16)pk;
          ((u16*)Cout)[(size_t)bz * sC + ci0 + Nc] = (u16)(pk >> 16);
        } else if (EPI == 1) {
          float v0 = aux1[(size_t)bz * sAux1 + ci0];
          float v1 = aux1[(size_t)bz * sAux1 + ci0 + Nc];
          unsigned pk = cvt_pk_bf16(v0 - a4[rp * 2], v1 - a4[rp * 2 + 1]);
          ((u16*)Cout)[(size_t)bz * sC + ci0] = (u16)pk;
          ((u16*)Cout)[(size_t)bz * sC + ci0 + Nc] = (u16)(pk >> 16);
        } else if (EPI == 3) {
          float b2v = aux2[gcol];
          unsigned pk = cvt_pk_bf16(gelu_fast(a4[rp * 2] + b2v),
                                    gelu_fast(a4[rp * 2 + 1] + b2v));
          ((u16*)Cout)[ci0] = (u16)pk;
          ((u16*)Cout)[ci0 + Nc] = (u16)(pk >> 16);
        } else if (EPI == 6) {  // bf16(acc + bias + f32 residual)
          float b2v = aux2[gcol];
          unsigned pk = cvt_pk_bf16(a4[rp * 2] + b2v + aux1[ci0],
                                    a4[rp * 2 + 1] + b2v + aux1[ci0 + Nc]);
          ((u16*)Cout)[ci0] = (u16)pk;
          ((u16*)Cout)[ci0 + Nc] = (u16)(pk >> 16);
        } else {  // EPI == 7: bf16(acc + bias + bf16 residual)
          float b2v = aux2[gcol];
          const u16* r16 = (const u16*)aux1;
          unsigned pk = cvt_pk_bf16(a4[rp * 2] + b2v + bf2f(r16[ci0]),
                                    a4[rp * 2 + 1] + b2v + bf2f(r16[ci0 + Nc]));
          ((u16*)Cout)[ci0] = (u16)pk;
          ((u16*)Cout)[ci0 + Nc] = (u16)(pk >> 16);
        }
      }
    }
  }
}

// ------------------------- launch -------------------------

extern "C" void kernel_launch(void* const* d_in, const int* in_sizes, int n_in,
                              void* d_out, int out_size, void* d_ws, size_t ws_size,
                              hipStream_t stream) {
  const float* q      = (const float*)d_in[0];
  const float* k      = (const float*)d_in[1];
  const float* v      = (const float*)d_in[2];
  const float* W_diff = (const float*)d_in[3];
  const float* b_diff = (const float*)d_in[4];
  const float* ln_g   = (const float*)d_in[5];
  const float* ln_b   = (const float*)d_in[6];
  const float* W1     = (const float*)d_in[7];
  const float* b1     = (const float*)d_in[8];
  const float* W2     = (const float*)d_in[9];
  const float* b2     = (const float*)d_in[10];

  const int B = 8, N = 2048, D = 1024, H = 4096;
  char* ws = (char*)d_ws;
  u16* A    = (u16*)(ws + 0);
  u16* Bm   = (u16*)(ws + 33554432);
  u16* X    = (u16*)(ws + 33554432);   // reuses Bm after GEMM1
  u16* Vt   = (u16*)(ws + 67108864);
  u16* S    = (u16*)(ws + 100663296);
  u16* Hbf  = (u16*)(ws + 134217728);  // LN1 out; reused as bf16 interim by GEMM5
  u16* Wd   = (u16*)(ws + 167772160);
  u16* W1b  = (u16*)(ws + 169869312);
  u16* W2b  = (u16*)(ws + 178257920);
  u16* G    = (u16*)(ws + 0);          // 134M, aliases A/X/Vt/S-low
  u16* Fbf  = (u16*)d_out;             // f_diff bf16 lives in d_out
  float* out = (float*)d_out;

  cast3_kernel<<<9216, 256, 0, stream>>>(W_diff, W1, W2, Wd, W1b, W2b);

  prob_kernel<<<B * N, 256, 0, stream>>>(q, k, A, Bm);
  transpose_v_kernel<<<dim3(D / 32, N / 32, B), 256, 0, stream>>>(v, Vt);

  // GEMM1: S = bf16(-(A @ Bm^T)/32)   grid 8x16x8 = 1024
  gemm8_kernel<0><<<1024, 512, 0, stream>>>(
      A, Bm, S, nullptr, nullptr, N, N, D,
      (long)N * D, (long)N * D, (long)N * N, 0, -0.03125f);

  softmax_rows_kernel<<<B * N, 256, 0, stream>>>(S);

  // GEMM2: X = bf16(v - attn @ v)     grid 8x8x8 = 512
  gemm8_kernel<1><<<512, 512, 0, stream>>>(
      S, Vt, X, v, nullptr, N, D, N,
      (long)N * N, (long)D * N, (long)N * D, (long)N * D, 1.0f);

  // GEMM3: f_diff = bf16(X @ Wd^T + b_diff + q) -> Fbf   grid 64x8 = 512
  gemm8_kernel<6><<<512, 512, 0, stream>>>(
      X, Wd, Fbf, q, b_diff, B * N, D, D, 0, 0, 0, 0, 1.0f);

  // h = bf16(LN(f_diff))
  layernorm_rows_kernel<1, 1><<<B * N, 256, 0, stream>>>(Fbf, Hbf, ln_g, ln_b);

  // GEMM4: G = bf16(gelu(h @ W1^T + b1))   grid 64x32 = 2048
  gemm8_kernel<3><<<2048, 512, 0, stream>>>(
      Hbf, W1b, G, nullptr, b1, B * N, H, D, 0, 0, 0, 0, 1.0f);

  // GEMM5: interim = bf16(G @ W2^T + b2 + f_diff) -> Hbf   grid 64x8 = 512
  gemm8_kernel<7><<<512, 512, 0, stream>>>(
      G, W2b, Hbf, (const float*)Fbf, b2, B * N, D, H, 0, 0, 0, 0, 1.0f);

  // final LN: bf16 interim -> f32 d_out (overwrites Fbf, which is dead)
  layernorm_rows_kernel<1, 0><<<B * N, 256, 0, stream>>>(Hbf, out, ln_g, ln_b);
}

// Round 17
// 586.178 us; speedup vs baseline: 1.0702x; 1.0702x over previous
//
#include <hip/hip_runtime.h>
#include <math.h>

typedef unsigned short u16;
typedef __attribute__((ext_vector_type(4))) unsigned short u16x4;
typedef __attribute__((ext_vector_type(8))) short s16x8;
typedef __attribute__((ext_vector_type(4))) float f32x4;
typedef __attribute__((ext_vector_type(4))) float f4v;

#define DEVI static __device__ __forceinline__

DEVI u16 f2bf(float f) {
  union { float f; unsigned u; } c; c.f = f;
  return (u16)((c.u + 0x7FFFu + ((c.u >> 16) & 1u)) >> 16);
}
DEVI float bf2f(u16 h) {
  union { unsigned u; float f; } c; c.u = ((unsigned)h) << 16;
  return c.f;
}
DEVI unsigned cvt_pk_bf16(float lo, float hi) {  // [15:0]=bf16(lo),[31:16]=bf16(hi), RNE
  unsigned r;
  asm("v_cvt_pk_bf16_f32 %0, %1, %2" : "=v"(r) : "v"(lo), "v"(hi));
  return r;
}

DEVI float tanh_fast(float x) {          // branch-free: 1-2/(e^{2x}+1)
  float e = __expf(2.0f * x);
  float r = __builtin_amdgcn_rcpf(e + 1.0f);
  return fmaf(-2.0f, r, 1.0f);
}
DEVI float gelu_fast(float x) {          // tanh-form gelu
  float x2 = x * x;
  float u = x * fmaf(x2, 0.0356774081f, 0.7978845608f);
  float e = __expf(2.0f * u);
  float r = __builtin_amdgcn_rcpf(e + 1.0f);
  float t = fmaf(-2.0f, r, 1.0f);
  float hx = 0.5f * x;
  return fmaf(hx, t, hx);
}

DEVI void load_lds16(const u16* g, u16* l) {
  __builtin_amdgcn_global_load_lds(
      (const __attribute__((address_space(1))) void*)g,
      (__attribute__((address_space(3))) void*)l, 16, 0, 0);
}

// Round-17: barriers carry ONLY the counted vmcnt. No explicit lgkmcnt(0),
// no sched_barrier, no setprio — the compiler inserts minimal counted lgkm
// waits for the C++ ds_read->MFMA deps and can interleave the pipes.
#define BARP() asm volatile("s_barrier" ::: "memory")
#define BARP_VM4() asm volatile("s_waitcnt vmcnt(4)\n\ts_barrier" ::: "memory")
#define BARP_VM0() asm volatile("s_waitcnt vmcnt(0)\n\ts_barrier" ::: "memory")

// ------------------------- small kernels -------------------------

// fused weight casts: W_diff (1M f32), W1 (4M), W2 (4M) -> bf16
__global__ __launch_bounds__(256) void cast3_kernel(
    const float* __restrict__ wd, const float* __restrict__ w1,
    const float* __restrict__ w2, u16* __restrict__ owd,
    u16* __restrict__ ow1, u16* __restrict__ ow2) {
  const int n1 = 262144, n2 = 1048576;  // in float4 units
  int i = blockIdx.x * 256 + threadIdx.x;
  const float* src; u16* dst; int j;
  if (i < n1) { src = wd; dst = owd; j = i; }
  else if (i < n1 + n2) { src = w1; dst = ow1; j = i - n1; }
  else { src = w2; dst = ow2; j = i - n1 - n2; }
  f4v f = ((const f4v*)src)[j];
  u16x4 o;
  o[0] = f2bf(f[0]); o[1] = f2bf(f[1]); o[2] = f2bf(f[2]); o[3] = f2bf(f[3]);
  ((u16x4*)dst)[j] = o;
}

__global__ __launch_bounds__(256) void prob_kernel(
    const float* __restrict__ q, const float* __restrict__ k,
    u16* __restrict__ A, u16* __restrict__ Bm) {
  const int D = 1024;
  size_t row = blockIdx.x;
  int t = threadIdx.x;
  f4v qv = ((const f4v*)(q + row * D))[t];
  f4v kv = ((const f4v*)(k + row * D))[t];
  float tq[4], tk[4];
  float sq = 0.f, sk = 0.f;
#pragma unroll
  for (int i = 0; i < 4; i++) {
    tq[i] = tanh_fast(qv[i]) * 0.499f + 0.5f;
    tk[i] = tanh_fast(kv[i]) * 0.499f + 0.5f;
    sq += tq[i]; sk += tk[i];
  }
#pragma unroll
  for (int off = 32; off > 0; off >>= 1) {
    sq += __shfl_xor(sq, off);
    sk += __shfl_xor(sk, off);
  }
  __shared__ float sbq[4], sbk[4];
  int lane = t & 63, w = t >> 6;
  if (lane == 0) { sbq[w] = sq; sbk[w] = sk; }
  __syncthreads();
  sq = sbq[0] + sbq[1] + sbq[2] + sbq[3];
  sk = sbk[0] + sbk[1] + sbk[2] + sbk[3];
  float iq = 1.0f / (sq + 1e-8f), ik = 1.0f / (sk + 1e-8f);
  u16x4 av, bv;
#pragma unroll
  for (int i = 0; i < 4; i++) {
    float qp = fmaxf(tq[i] * iq, 1e-8f);
    float kp = fmaxf(tk[i] * ik, 1e-8f);
    av[i] = f2bf(qp - kp);
    bv[i] = f2bf(__logf(qp) - __logf(kp));
  }
  ((u16x4*)(A + row * D))[t] = av;
  ((u16x4*)(Bm + row * D))[t] = bv;
}

__global__ __launch_bounds__(256) void transpose_v_kernel(
    const float* __restrict__ v, u16* __restrict__ Vt) {
  const int N = 2048, D = 1024;
  __shared__ float tile[32][33];
  int b = blockIdx.z;
  int d0 = blockIdx.x * 32, n0 = blockIdx.y * 32;
  int tx = threadIdx.x & 31, ty = threadIdx.x >> 5;
  const float* vb = v + (size_t)b * N * D;
  u16* vtb = Vt + (size_t)b * N * D;
#pragma unroll
  for (int i = 0; i < 4; i++)
    tile[ty + i * 8][tx] = vb[(size_t)(n0 + ty + i * 8) * D + d0 + tx];
  __syncthreads();
#pragma unroll
  for (int i = 0; i < 4; i++)
    vtb[(size_t)(d0 + ty + i * 8) * N + n0 + tx] = f2bf(tile[tx][ty + i * 8]);
}

__global__ __launch_bounds__(256) void softmax_rows_kernel(u16* __restrict__ S) {
  const int NN = 2048;
  size_t row = blockIdx.x;
  u16* r = S + row * NN;
  int t = threadIdx.x;
  s16x8 vv = ((const s16x8*)r)[t];
  float x[8];
  float mx = -1e30f;
#pragma unroll
  for (int i = 0; i < 8; i++) { x[i] = bf2f((u16)vv[i]); mx = fmaxf(mx, x[i]); }
#pragma unroll
  for (int off = 32; off > 0; off >>= 1) mx = fmaxf(mx, __shfl_xor(mx, off));
  __shared__ float sm[4], ss[4];
  int lane = t & 63, w = t >> 6;
  if (lane == 0) sm[w] = mx;
  __syncthreads();
  mx = fmaxf(fmaxf(sm[0], sm[1]), fmaxf(sm[2], sm[3]));
  float sum = 0.f;
#pragma unroll
  for (int i = 0; i < 8; i++) { x[i] = __expf(x[i] - mx); sum += x[i]; }
#pragma unroll
  for (int off = 32; off > 0; off >>= 1) sum += __shfl_xor(sum, off);
  if (lane == 0) ss[w] = sum;
  __syncthreads();
  float inv = 1.0f / (ss[0] + ss[1] + ss[2] + ss[3]);
  s16x8 ov;
#pragma unroll
  for (int i = 0; i < 8; i++) ov[i] = (short)f2bf(x[i] * inv);
  ((s16x8*)r)[t] = ov;
}

// LN rows of 1024. IN_BF16: input u16*, else f32*. OUT_BF16: out u16*, else f32*.
template <int IN_BF16, int OUT_BF16>
__global__ __launch_bounds__(256) void layernorm_rows_kernel(
    const void* __restrict__ inp, void* __restrict__ outp,
    const float* __restrict__ g, const float* __restrict__ bia) {
  const int D = 1024;
  size_t row = blockIdx.x;
  int t = threadIdx.x;
  f4v xv;
  if (IN_BF16) {
    u16x4 h4 = ((const u16x4*)inp)[row * (D / 4) + t];
    xv[0] = bf2f(h4[0]); xv[1] = bf2f(h4[1]); xv[2] = bf2f(h4[2]); xv[3] = bf2f(h4[3]);
  } else {
    xv = ((const f4v*)inp)[row * (D / 4) + t];
  }
  float s = xv[0] + xv[1] + xv[2] + xv[3];
  float s2 = xv[0] * xv[0] + xv[1] * xv[1] + xv[2] * xv[2] + xv[3] * xv[3];
#pragma unroll
  for (int off = 32; off > 0; off >>= 1) {
    s += __shfl_xor(s, off);
    s2 += __shfl_xor(s2, off);
  }
  __shared__ float sa[4], sb[4];
  int lane = t & 63, w = t >> 6;
  if (lane == 0) { sa[w] = s; sb[w] = s2; }
  __syncthreads();
  s = sa[0] + sa[1] + sa[2] + sa[3];
  s2 = sb[0] + sb[1] + sb[2] + sb[3];
  float mean = s * (1.0f / D);
  float var = s2 * (1.0f / D) - mean * mean;
  float rs = rsqrtf(var + 1e-5f);
  f4v gv = ((const f4v*)g)[t];
  f4v bv = ((const f4v*)bia)[t];
  float y[4];
#pragma unroll
  for (int i = 0; i < 4; i++) y[i] = (xv[i] - mean) * rs * gv[i] + bv[i];
  if (OUT_BF16) {
    u16x4 o; o[0] = f2bf(y[0]); o[1] = f2bf(y[1]); o[2] = f2bf(y[2]); o[3] = f2bf(y[3]);
    ((u16x4*)outp)[row * (D / 4) + t] = o;
  } else {
    f4v o; o[0] = y[0]; o[1] = y[1]; o[2] = y[2]; o[3] = y[3];
    ((f4v*)outp)[row * (D / 4) + t] = o;
  }
}

// --------------- 8-phase 256x256 NT GEMM ---------------
// Round-17 = round-13 (verified 552us base: schedule, ledger, peel, epilogue
// all identical) with the scheduling straitjacket removed: NO setprio, NO
// explicit lgkmcnt(0), NO sched_barrier. Barriers carry only counted vmcnt.
// The compiler tracks the C++ ds_read -> MFMA deps and emits minimal counted
// lgkm waits, letting the LDS and matrix pipes interleave instead of the
// convoy (measured 1196 cyc/phase = 576 LDS + 620 MFMA, fully serial).
// Ledger (verified r10-13): vmcnt(4) at ph4/ph8 only; prologue vm4; peel
// full-drain at e-ph4 then barrier-free tail.
// EPI 0: C=bf16(acc*scale)  1: C=bf16(aux1-acc)  3: C=bf16(gelu(acc+aux2))
// 6: C=bf16(acc+aux2[col]+f32 aux1[ci])  7: C=bf16(acc+aux2[col]+bf16 aux1[ci])
template <int EPI>
__global__ __launch_bounds__(512, 2) void gemm8_kernel(
    const u16* __restrict__ Ab, const u16* __restrict__ Bb,
    void* __restrict__ Cout,
    const float* __restrict__ aux1, const float* __restrict__ aux2,
    int M, int Nc, int K,
    long sA, long sB, long sC, long sAux1, float scale) {
  __shared__ u16 lds[65536];

  int nwg = gridDim.x;
  int orig = blockIdx.x;
  int swz = (orig & 7) * (nwg >> 3) + (orig >> 3);
  int gxm = M >> 8, gyn = Nc >> 8;
  int pb = gxm * gyn;
  int bz = swz / pb;
  int rem = swz - bz * pb;
  // grouped raster: group = 8 bx-panels x gyn by-panels, bx fastest in group
  int gsz = gyn << 3;
  int gid = rem / gsz;
  int lr = rem - gid * gsz;
  int bx = (gid << 3) + (lr & 7);
  int by = lr >> 3;
  int m0 = bx << 8, n0 = by << 8;

  const u16* Ap = Ab + (size_t)bz * sA;
  const u16* Bp = Bb + (size_t)bz * sB;

  int t = threadIdx.x, wid = t >> 6, l = t & 63;
  int wr = wid >> 2, wc = wid & 3;
  int sr = l >> 3;
  int scb = ((l & 7) ^ sr) * 8;
  int frow = l & 15, fq = l >> 4, fx = l & 7;

  // ---- running stage pointers (advance +128 elems / iteration) ----
  const size_t rowoff = (size_t)(wid * 16 + sr) * K + scb;
  const u16* pA0 = Ap + (size_t)m0 * K + rowoff;   // A half0, tile base
  const u16* pA0h = pA0 + (size_t)8 * K;
  const u16* pA1 = pA0 + (size_t)128 * K;          // A half1
  const u16* pA1h = pA1 + (size_t)8 * K;
  const u16* pB0 = Bp + (size_t)n0 * K + rowoff;
  const u16* pB0h = pB0 + (size_t)8 * K;
  const u16* pB1 = pB0 + (size_t)128 * K;
  const u16* pB1h = pB1 + (size_t)8 * K;
  u16* ldA = &lds[wid * 1024];
  u16* ldB = ldA + 32768;

  // ---- precomputed thread-invariant LDS read byte offsets ----
  int aoffs[4][2], boffs[2][2];
#pragma unroll
  for (int m = 0; m < 4; m++)
#pragma unroll
    for (int kk = 0; kk < 2; kk++)
      aoffs[m][kk] = ((wr * 64 + m * 16 + frow) * 64 + ((kk * 4 + fq) ^ fx) * 8) * 2;
#pragma unroll
  for (int n = 0; n < 2; n++)
#pragma unroll
    for (int kk = 0; kk < 2; kk++)
      boffs[n][kk] = ((wc * 32 + n * 16 + frow) * 64 + ((kk * 4 + fq) ^ fx) * 8) * 2 + 65536;

  s16x8 af[4][2], bf0[2][2], bf1[2][2];
  auto rdA = [&](int sl, int h) {
#pragma unroll
    for (int m = 0; m < 4; m++)
#pragma unroll
      for (int kk = 0; kk < 2; kk++)
        af[m][kk] = *(const s16x8*)((const char*)lds +
                                    (aoffs[m][kk] + (sl * 32768 + h * 16384)));
  };
  auto rdB = [&](int sl, int h, s16x8 (&bf)[2][2]) {
#pragma unroll
    for (int n = 0; n < 2; n++)
#pragma unroll
      for (int kk = 0; kk < 2; kk++)
        bf[n][kk] = *(const s16x8*)((const char*)lds +
                                    (boffs[n][kk] + (sl * 32768 + h * 16384)));
  };

  f32x4 acc[2][2][4][2];
#pragma unroll
  for (int a = 0; a < 2; a++)
#pragma unroll
    for (int b = 0; b < 2; b++)
#pragma unroll
      for (int m = 0; m < 4; m++)
#pragma unroll
        for (int n = 0; n < 2; n++) acc[a][b][m][n] = (f32x4){0.f, 0.f, 0.f, 0.f};

#define MFMA_Q(QM, QN, BF)                                                    \
  do {                                                                        \
    _Pragma("unroll") for (int m = 0; m < 4; m++)                             \
        _Pragma("unroll") for (int n = 0; n < 2; n++)                         \
        _Pragma("unroll") for (int kk = 0; kk < 2; kk++)                      \
            acc[QM][QN][m][n] = __builtin_amdgcn_mfma_f32_16x16x32_bf16(      \
                af[m][kk], BF[n][kk], acc[QM][QN][m][n], 0, 0, 0);            \
  } while (0)

  // prologue: stA(0,0) stB(0,1) stB(0,0) stA(0,1) stA(1,0) stB(1,1)
  load_lds16(pA0, ldA);              load_lds16(pA0h, ldA + 512);
  load_lds16(pB1, ldB + 8192);       load_lds16(pB1h, ldB + 8192 + 512);
  load_lds16(pB0, ldB);              load_lds16(pB0h, ldB + 512);
  load_lds16(pA1, ldA + 8192);       load_lds16(pA1h, ldA + 8192 + 512);
  load_lds16(pA0 + 64, ldA + 16384); load_lds16(pA0h + 64, ldA + 16384 + 512);
  load_lds16(pB1 + 64, ldB + 16384 + 8192);
  load_lds16(pB1h + 64, ldB + 16384 + 8192 + 512);
  BARP_VM4();

  int nt = K >> 6, niter = nt >> 1;
  for (int i = 0; i < niter - 1; i++) {
    rdA(0, 0); rdB(0, 0, bf0);
    load_lds16(pB0 + 64, ldB + 16384);
    load_lds16(pB0h + 64, ldB + 16384 + 512);
    BARP(); MFMA_Q(0, 0, bf0);
    rdB(0, 1, bf1);
    load_lds16(pA1 + 64, ldA + 16384 + 8192);
    load_lds16(pA1h + 64, ldA + 16384 + 8192 + 512);
    BARP(); MFMA_Q(0, 1, bf1);
    rdA(0, 1);
    load_lds16(pA0 + 128, ldA);
    load_lds16(pA0h + 128, ldA + 512);
    BARP(); MFMA_Q(1, 1, bf1);
    load_lds16(pB1 + 128, ldB + 8192);
    load_lds16(pB1h + 128, ldB + 8192 + 512);
    BARP_VM4(); MFMA_Q(1, 0, bf0);
    rdA(1, 0); rdB(1, 0, bf0);
    load_lds16(pB0 + 128, ldB);
    load_lds16(pB0h + 128, ldB + 512);
    BARP(); MFMA_Q(0, 0, bf0);
    rdB(1, 1, bf1);
    load_lds16(pA1 + 128, ldA + 8192);
    load_lds16(pA1h + 128, ldA + 8192 + 512);
    BARP(); MFMA_Q(0, 1, bf1);
    rdA(1, 1);
    load_lds16(pA0 + 192, ldA + 16384);
    load_lds16(pA0h + 192, ldA + 16384 + 512);
    BARP(); MFMA_Q(1, 1, bf1);
    load_lds16(pB1 + 192, ldB + 16384 + 8192);
    load_lds16(pB1h + 192, ldB + 16384 + 8192 + 512);
    BARP_VM4(); MFMA_Q(1, 0, bf0);
    pA0 += 128; pA0h += 128; pA1 += 128; pA1h += 128;
    pB0 += 128; pB0h += 128; pB1 += 128; pB1h += 128;
  }
  // peeled final iteration (round-10/13 verified form). Entering outstanding=4.
  {
    rdA(0, 0); rdB(0, 0, bf0);
    load_lds16(pB0 + 64, ldB + 16384);
    load_lds16(pB0h + 64, ldB + 16384 + 512);
    BARP(); MFMA_Q(0, 0, bf0);
    rdB(0, 1, bf1);
    load_lds16(pA1 + 64, ldA + 16384 + 8192);
    load_lds16(pA1h + 64, ldA + 16384 + 8192 + 512);
    BARP(); MFMA_Q(0, 1, bf1);
    rdA(0, 1);
    BARP(); MFMA_Q(1, 1, bf1);
    BARP_VM0(); MFMA_Q(1, 0, bf0);   // drain + publish all staged LDS
    rdA(1, 0); rdB(1, 0, bf0);
    MFMA_Q(0, 0, bf0);
    rdB(1, 1, bf1);
    MFMA_Q(0, 1, bf1);
    rdA(1, 1);
    MFMA_Q(1, 1, bf1);
    MFMA_Q(1, 0, bf0);
  }
#undef MFMA_Q

  // epilogue: rows fq*4+r, col frow; bf16 rounding via cvt_pk
#pragma unroll
  for (int qm = 0; qm < 2; qm++) {
#pragma unroll
    for (int qn = 0; qn < 2; qn++) {
#pragma unroll
      for (int m = 0; m < 4; m++) {
#pragma unroll
        for (int n = 0; n < 2; n++) {
          f32x4 a4 = acc[qm][qn][m][n];
          int gcol = n0 + qn * 128 + wc * 32 + n * 16 + frow;
#pragma unroll
          for (int rp = 0; rp < 2; rp++) {
            int grow0 = m0 + qm * 128 + wr * 64 + m * 16 + fq * 4 + rp * 2;
            size_t ci0 = (size_t)grow0 * Nc + gcol;
            if (EPI == 0) {
              unsigned pk = cvt_pk_bf16(a4[rp * 2] * scale, a4[rp * 2 + 1] * scale);
              ((u16*)Cout)[(size_t)bz * sC + ci0] = (u16)pk;
              ((u16*)Cout)[(size_t)bz * sC + ci0 + Nc] = (u16)(pk >> 16);
            } else if (EPI == 1) {
              float v0 = aux1[(size_t)bz * sAux1 + ci0];
              float v1 = aux1[(size_t)bz * sAux1 + ci0 + Nc];
              unsigned pk = cvt_pk_bf16(v0 - a4[rp * 2], v1 - a4[rp * 2 + 1]);
              ((u16*)Cout)[(size_t)bz * sC + ci0] = (u16)pk;
              ((u16*)Cout)[(size_t)bz * sC + ci0 + Nc] = (u16)(pk >> 16);
            } else if (EPI == 3) {
              float b2v = aux2[gcol];
              unsigned pk = cvt_pk_bf16(gelu_fast(a4[rp * 2] + b2v),
                                        gelu_fast(a4[rp * 2 + 1] + b2v));
              ((u16*)Cout)[ci0] = (u16)pk;
              ((u16*)Cout)[ci0 + Nc] = (u16)(pk >> 16);
            } else if (EPI == 6) {  // bf16(acc + bias + f32 residual)
              float b2v = aux2[gcol];
              unsigned pk = cvt_pk_bf16(a4[rp * 2] + b2v + aux1[ci0],
                                        a4[rp * 2 + 1] + b2v + aux1[ci0 + Nc]);
              ((u16*)Cout)[ci0] = (u16)pk;
              ((u16*)Cout)[ci0 + Nc] = (u16)(pk >> 16);
            } else {  // EPI == 7: bf16(acc + bias + bf16 residual)
              float b2v = aux2[gcol];
              const u16* r16 = (const u16*)aux1;
              unsigned pk = cvt_pk_bf16(a4[rp * 2] + b2v + bf2f(r16[ci0]),
                                        a4[rp * 2 + 1] + b2v + bf2f(r16[ci0 + Nc]));
              ((u16*)Cout)[ci0] = (u16)pk;
              ((u16*)Cout)[ci0 + Nc] = (u16)(pk >> 16);
            }
          }
        }
      }
    }
  }
}

// ------------------------- launch -------------------------

extern "C" void kernel_launch(void* const* d_in, const int* in_sizes, int n_in,
                              void* d_out, int out_size, void* d_ws, size_t ws_size,
                              hipStream_t stream) {
  const float* q      = (const float*)d_in[0];
  const float* k      = (const float*)d_in[1];
  const float* v      = (const float*)d_in[2];
  const float* W_diff = (const float*)d_in[3];
  const float* b_diff = (const float*)d_in[4];
  const float* ln_g   = (const float*)d_in[5];
  const float* ln_b   = (const float*)d_in[6];
  const float* W1     = (const float*)d_in[7];
  const float* b1     = (const float*)d_in[8];
  const float* W2     = (const float*)d_in[9];
  const float* b2     = (const float*)d_in[10];

  const int B = 8, N = 2048, D = 1024, H = 4096;
  char* ws = (char*)d_ws;
  u16* A    = (u16*)(ws + 0);
  u16* Bm   = (u16*)(ws + 33554432);
  u16* X    = (u16*)(ws + 33554432);   // reuses Bm after GEMM1
  u16* Vt   = (u16*)(ws + 67108864);
  u16* S    = (u16*)(ws + 100663296);
  u16* Hbf  = (u16*)(ws + 134217728);  // LN1 out; reused as bf16 interim by GEMM5
  u16* Wd   = (u16*)(ws + 167772160);
  u16* W1b  = (u16*)(ws + 169869312);
  u16* W2b  = (u16*)(ws + 178257920);
  u16* G    = (u16*)(ws + 0);          // 134M, aliases A/X/Vt/S-low
  u16* Fbf  = (u16*)d_out;             // f_diff bf16 lives in d_out
  float* out = (float*)d_out;

  cast3_kernel<<<9216, 256, 0, stream>>>(W_diff, W1, W2, Wd, W1b, W2b);

  prob_kernel<<<B * N, 256, 0, stream>>>(q, k, A, Bm);
  transpose_v_kernel<<<dim3(D / 32, N / 32, B), 256, 0, stream>>>(v, Vt);

  // GEMM1: S = bf16(-(A @ Bm^T)/32)
  gemm8_kernel<0><<<8 * 8 * 8, 512, 0, stream>>>(
      A, Bm, S, nullptr, nullptr, N, N, D,
      (long)N * D, (long)N * D, (long)N * N, 0, -0.03125f);

  softmax_rows_kernel<<<B * N, 256, 0, stream>>>(S);

  // GEMM2: X = bf16(v - attn @ v)
  gemm8_kernel<1><<<8 * 4 * 8, 512, 0, stream>>>(
      S, Vt, X, v, nullptr, N, D, N,
      (long)N * N, (long)D * N, (long)N * D, (long)N * D, 1.0f);

  // GEMM3: f_diff = bf16(X @ Wd^T + b_diff + q) -> Fbf (in d_out)
  gemm8_kernel<6><<<64 * 4, 512, 0, stream>>>(
      X, Wd, Fbf, q, b_diff, B * N, D, D, 0, 0, 0, 0, 1.0f);

  // h = bf16(LN(f_diff))
  layernorm_rows_kernel<1, 1><<<B * N, 256, 0, stream>>>(Fbf, Hbf, ln_g, ln_b);

  // GEMM4: G = bf16(gelu(h @ W1^T + b1))
  gemm8_kernel<3><<<64 * 16, 512, 0, stream>>>(
      Hbf, W1b, G, nullptr, b1, B * N, H, D, 0, 0, 0, 0, 1.0f);

  // GEMM5: interim = bf16(G @ W2^T + b2 + f_diff) -> Hbf slot (dead after GEMM4)
  gemm8_kernel<7><<<64 * 4, 512, 0, stream>>>(
      G, W2b, Hbf, (const float*)Fbf, b2, B * N, D, H, 0, 0, 0, 0, 1.0f);

  // final LN: bf16 interim -> f32 d_out (overwrites Fbf, which is dead)
  layernorm_rows_kernel<1, 0><<<B * N, 256, 0, stream>>>(Hbf, out, ln_g, ln_b);
}

// Round 18
// 544.055 us; speedup vs baseline: 1.1531x; 1.0774x over previous
//
#include <hip/hip_runtime.h>
#include <math.h>

typedef unsigned short u16;
typedef __attribute__((ext_vector_type(4))) unsigned short u16x4;
typedef __attribute__((ext_vector_type(8))) short s16x8;
typedef __attribute__((ext_vector_type(4))) float f32x4;
typedef __attribute__((ext_vector_type(4))) float f4v;

#define DEVI static __device__ __forceinline__

DEVI u16 f2bf(float f) {
  union { float f; unsigned u; } c; c.f = f;
  return (u16)((c.u + 0x7FFFu + ((c.u >> 16) & 1u)) >> 16);
}
DEVI float bf2f(u16 h) {
  union { unsigned u; float f; } c; c.u = ((unsigned)h) << 16;
  return c.f;
}
DEVI unsigned cvt_pk_bf16(float lo, float hi) {  // [15:0]=bf16(lo),[31:16]=bf16(hi), RNE
  unsigned r;
  asm("v_cvt_pk_bf16_f32 %0, %1, %2" : "=v"(r) : "v"(lo), "v"(hi));
  return r;
}

DEVI float tanh_fast(float x) {          // branch-free: 1-2/(e^{2x}+1)
  float e = __expf(2.0f * x);
  float r = __builtin_amdgcn_rcpf(e + 1.0f);
  return fmaf(-2.0f, r, 1.0f);
}
DEVI float gelu_fast(float x) {          // tanh-form gelu
  float x2 = x * x;
  float u = x * fmaf(x2, 0.0356774081f, 0.7978845608f);
  float e = __expf(2.0f * u);
  float r = __builtin_amdgcn_rcpf(e + 1.0f);
  float t = fmaf(-2.0f, r, 1.0f);
  float hx = 0.5f * x;
  return fmaf(hx, t, hx);
}

DEVI void load_lds16(const u16* g, u16* l) {
  __builtin_amdgcn_global_load_lds(
      (const __attribute__((address_space(1))) void*)g,
      (__attribute__((address_space(3))) void*)l, 16, 0, 0);
}

// round-13 verified barrier forms: barrier -> single lgkm drain -> sched fence
#define BARL()                                                             \
  asm volatile("s_barrier\n\ts_waitcnt lgkmcnt(0)" ::: "memory");          \
  __builtin_amdgcn_sched_barrier(0)
#define BARL_VM4()                                                         \
  asm volatile("s_waitcnt vmcnt(4)\n\ts_barrier\n\ts_waitcnt lgkmcnt(0)" ::: "memory"); \
  __builtin_amdgcn_sched_barrier(0)
#define BARL_VM0()                                                         \
  asm volatile("s_waitcnt vmcnt(0)\n\ts_barrier\n\ts_waitcnt lgkmcnt(0)" ::: "memory"); \
  __builtin_amdgcn_sched_barrier(0)

// ------------------------- fused input-prep kernel -------------------------
// blocks [0,9216): weight casts; [9216,25600): prob; [25600,41984): V^T.
__global__ __launch_bounds__(256) void prep_kernel(
    const float* __restrict__ wd, const float* __restrict__ w1,
    const float* __restrict__ w2, u16* __restrict__ owd,
    u16* __restrict__ ow1, u16* __restrict__ ow2,
    const float* __restrict__ q, const float* __restrict__ k,
    u16* __restrict__ A, u16* __restrict__ Bm,
    const float* __restrict__ v, u16* __restrict__ Vt) {
  const int D = 1024, N = 2048;
  __shared__ float tile[32][33];  // transpose path (also covers prob's 8 floats)
  int blk = blockIdx.x;
  int t = threadIdx.x;

  if (blk < 9216) {
    // ---- weight casts: W_diff (262144 f4), W1 (1048576 f4), W2 (1048576 f4)
    const int n1 = 262144, n2 = 1048576;
    int i = blk * 256 + t;
    const float* src; u16* dst; int j;
    if (i < n1) { src = wd; dst = owd; j = i; }
    else if (i < n1 + n2) { src = w1; dst = ow1; j = i - n1; }
    else { src = w2; dst = ow2; j = i - n1 - n2; }
    f4v f = ((const f4v*)src)[j];
    u16x4 o;
    o[0] = f2bf(f[0]); o[1] = f2bf(f[1]); o[2] = f2bf(f[2]); o[3] = f2bf(f[3]);
    ((u16x4*)dst)[j] = o;
    return;
  }
  if (blk < 25600) {
    // ---- prob: one row of q,k
    size_t row = blk - 9216;
    f4v qv = ((const f4v*)(q + row * D))[t];
    f4v kv = ((const f4v*)(k + row * D))[t];
    float tq[4], tk[4];
    float sq = 0.f, sk = 0.f;
#pragma unroll
    for (int i = 0; i < 4; i++) {
      tq[i] = tanh_fast(qv[i]) * 0.499f + 0.5f;
      tk[i] = tanh_fast(kv[i]) * 0.499f + 0.5f;
      sq += tq[i]; sk += tk[i];
    }
#pragma unroll
    for (int off = 32; off > 0; off >>= 1) {
      sq += __shfl_xor(sq, off);
      sk += __shfl_xor(sk, off);
    }
    int lane = t & 63, w = t >> 6;
    float* sb = &tile[0][0];  // 8 floats of the shared tile
    if (lane == 0) { sb[w] = sq; sb[4 + w] = sk; }
    __syncthreads();
    sq = sb[0] + sb[1] + sb[2] + sb[3];
    sk = sb[4] + sb[5] + sb[6] + sb[7];
    float iq = 1.0f / (sq + 1e-8f), ik = 1.0f / (sk + 1e-8f);
    u16x4 av, bv;
#pragma unroll
    for (int i = 0; i < 4; i++) {
      float qp = fmaxf(tq[i] * iq, 1e-8f);
      float kp = fmaxf(tk[i] * ik, 1e-8f);
      av[i] = f2bf(qp - kp);
      bv[i] = f2bf(__logf(qp) - __logf(kp));
    }
    ((u16x4*)(A + row * D))[t] = av;
    ((u16x4*)(Bm + row * D))[t] = bv;
    return;
  }
  // ---- V^T: 32x32 tile; idx -> (b, n0, d0)
  int idx = blk - 25600;
  int b = idx >> 11;
  int rem = idx & 2047;
  int n0 = (rem >> 5) * 32;
  int d0 = (rem & 31) * 32;
  int tx = t & 31, ty = t >> 5;
  const float* vb = v + (size_t)b * N * D;
  u16* vtb = Vt + (size_t)b * N * D;
#pragma unroll
  for (int i = 0; i < 4; i++)
    tile[ty + i * 8][tx] = vb[(size_t)(n0 + ty + i * 8) * D + d0 + tx];
  __syncthreads();
#pragma unroll
  for (int i = 0; i < 4; i++)
    vtb[(size_t)(d0 + ty + i * 8) * N + n0 + tx] = f2bf(tile[tx][ty + i * 8]);
}

__global__ __launch_bounds__(256) void softmax_rows_kernel(u16* __restrict__ S) {
  const int NN = 2048;
  size_t row = blockIdx.x;
  u16* r = S + row * NN;
  int t = threadIdx.x;
  s16x8 vv = ((const s16x8*)r)[t];
  float x[8];
  float mx = -1e30f;
#pragma unroll
  for (int i = 0; i < 8; i++) { x[i] = bf2f((u16)vv[i]); mx = fmaxf(mx, x[i]); }
#pragma unroll
  for (int off = 32; off > 0; off >>= 1) mx = fmaxf(mx, __shfl_xor(mx, off));
  __shared__ float sm[4], ss[4];
  int lane = t & 63, w = t >> 6;
  if (lane == 0) sm[w] = mx;
  __syncthreads();
  mx = fmaxf(fmaxf(sm[0], sm[1]), fmaxf(sm[2], sm[3]));
  float sum = 0.f;
#pragma unroll
  for (int i = 0; i < 8; i++) { x[i] = __expf(x[i] - mx); sum += x[i]; }
#pragma unroll
  for (int off = 32; off > 0; off >>= 1) sum += __shfl_xor(sum, off);
  if (lane == 0) ss[w] = sum;
  __syncthreads();
  float inv = 1.0f / (ss[0] + ss[1] + ss[2] + ss[3]);
  s16x8 ov;
#pragma unroll
  for (int i = 0; i < 8; i++) ov[i] = (short)f2bf(x[i] * inv);
  ((s16x8*)r)[t] = ov;
}

// LN rows of 1024. IN_BF16: input u16*, else f32*. OUT_BF16: out u16*, else f32*.
template <int IN_BF16, int OUT_BF16>
__global__ __launch_bounds__(256) void layernorm_rows_kernel(
    const void* __restrict__ inp, void* __restrict__ outp,
    const float* __restrict__ g, const float* __restrict__ bia) {
  const int D = 1024;
  size_t row = blockIdx.x;
  int t = threadIdx.x;
  f4v xv;
  if (IN_BF16) {
    u16x4 h4 = ((const u16x4*)inp)[row * (D / 4) + t];
    xv[0] = bf2f(h4[0]); xv[1] = bf2f(h4[1]); xv[2] = bf2f(h4[2]); xv[3] = bf2f(h4[3]);
  } else {
    xv = ((const f4v*)inp)[row * (D / 4) + t];
  }
  float s = xv[0] + xv[1] + xv[2] + xv[3];
  float s2 = xv[0] * xv[0] + xv[1] * xv[1] + xv[2] * xv[2] + xv[3] * xv[3];
#pragma unroll
  for (int off = 32; off > 0; off >>= 1) {
    s += __shfl_xor(s, off);
    s2 += __shfl_xor(s2, off);
  }
  __shared__ float sa[4], sb[4];
  int lane = t & 63, w = t >> 6;
  if (lane == 0) { sa[w] = s; sb[w] = s2; }
  __syncthreads();
  s = sa[0] + sa[1] + sa[2] + sa[3];
  s2 = sb[0] + sb[1] + sb[2] + sb[3];
  float mean = s * (1.0f / D);
  float var = s2 * (1.0f / D) - mean * mean;
  float rs = rsqrtf(var + 1e-5f);
  f4v gv = ((const f4v*)g)[t];
  f4v bv = ((const f4v*)bia)[t];
  float y[4];
#pragma unroll
  for (int i = 0; i < 4; i++) y[i] = (xv[i] - mean) * rs * gv[i] + bv[i];
  if (OUT_BF16) {
    u16x4 o; o[0] = f2bf(y[0]); o[1] = f2bf(y[1]); o[2] = f2bf(y[2]); o[3] = f2bf(y[3]);
    ((u16x4*)outp)[row * (D / 4) + t] = o;
  } else {
    f4v o; o[0] = y[0]; o[1] = y[1]; o[2] = y[2]; o[3] = y[3];
    ((f4v*)outp)[row * (D / 4) + t] = o;
  }
}

// --------------- 8-phase 256x256 NT GEMM (round-13 verified form) ---------------
// Best-verified configuration (552 us total). Schedule: one barrier/phase
// (post-barrier single lgkmcnt(0) + sched fence), setprio around MFMA bursts,
// vmcnt(4) at ph4/ph8 only, running stage pointers + precomputed LDS read
// offsets, peel with full drain at e-ph4 then barrier-free tail.
// EPI 0: C=bf16(acc*scale)  1: C=bf16(aux1-acc)  3: C=bf16(gelu(acc+aux2))
// 6: C=bf16(acc+aux2[col]+f32 aux1[ci])  7: C=bf16(acc+aux2[col]+bf16 aux1[ci])
template <int EPI>
__global__ __launch_bounds__(512, 2) void gemm8_kernel(
    const u16* __restrict__ Ab, const u16* __restrict__ Bb,
    void* __restrict__ Cout,
    const float* __restrict__ aux1, const float* __restrict__ aux2,
    int M, int Nc, int K,
    long sA, long sB, long sC, long sAux1, float scale) {
  __shared__ u16 lds[65536];

  int nwg = gridDim.x;
  int orig = blockIdx.x;
  int swz = (orig & 7) * (nwg >> 3) + (orig >> 3);
  int gxm = M >> 8, gyn = Nc >> 8;
  int pb = gxm * gyn;
  int bz = swz / pb;
  int rem = swz - bz * pb;
  int gsz = gyn << 3;
  int gid = rem / gsz;
  int lr = rem - gid * gsz;
  int bx = (gid << 3) + (lr & 7);
  int by = lr >> 3;
  int m0 = bx << 8, n0 = by << 8;

  const u16* Ap = Ab + (size_t)bz * sA;
  const u16* Bp = Bb + (size_t)bz * sB;

  int t = threadIdx.x, wid = t >> 6, l = t & 63;
  int wr = wid >> 2, wc = wid & 3;
  int sr = l >> 3;
  int scb = ((l & 7) ^ sr) * 8;
  int frow = l & 15, fq = l >> 4, fx = l & 7;

  const size_t rowoff = (size_t)(wid * 16 + sr) * K + scb;
  const u16* pA0 = Ap + (size_t)m0 * K + rowoff;
  const u16* pA0h = pA0 + (size_t)8 * K;
  const u16* pA1 = pA0 + (size_t)128 * K;
  const u16* pA1h = pA1 + (size_t)8 * K;
  const u16* pB0 = Bp + (size_t)n0 * K + rowoff;
  const u16* pB0h = pB0 + (size_t)8 * K;
  const u16* pB1 = pB0 + (size_t)128 * K;
  const u16* pB1h = pB1 + (size_t)8 * K;
  u16* ldA = &lds[wid * 1024];
  u16* ldB = ldA + 32768;

  int aoffs[4][2], boffs[2][2];
#pragma unroll
  for (int m = 0; m < 4; m++)
#pragma unroll
    for (int kk = 0; kk < 2; kk++)
      aoffs[m][kk] = ((wr * 64 + m * 16 + frow) * 64 + ((kk * 4 + fq) ^ fx) * 8) * 2;
#pragma unroll
  for (int n = 0; n < 2; n++)
#pragma unroll
    for (int kk = 0; kk < 2; kk++)
      boffs[n][kk] = ((wc * 32 + n * 16 + frow) * 64 + ((kk * 4 + fq) ^ fx) * 8) * 2 + 65536;

  s16x8 af[4][2], bf0[2][2], bf1[2][2];
  auto rdA = [&](int sl, int h) {
#pragma unroll
    for (int m = 0; m < 4; m++)
#pragma unroll
      for (int kk = 0; kk < 2; kk++)
        af[m][kk] = *(const s16x8*)((const char*)lds +
                                    (aoffs[m][kk] + (sl * 32768 + h * 16384)));
  };
  auto rdB = [&](int sl, int h, s16x8 (&bf)[2][2]) {
#pragma unroll
    for (int n = 0; n < 2; n++)
#pragma unroll
      for (int kk = 0; kk < 2; kk++)
        bf[n][kk] = *(const s16x8*)((const char*)lds +
                                    (boffs[n][kk] + (sl * 32768 + h * 16384)));
  };

  f32x4 acc[2][2][4][2];
#pragma unroll
  for (int a = 0; a < 2; a++)
#pragma unroll
    for (int b = 0; b < 2; b++)
#pragma unroll
      for (int m = 0; m < 4; m++)
#pragma unroll
        for (int n = 0; n < 2; n++) acc[a][b][m][n] = (f32x4){0.f, 0.f, 0.f, 0.f};

#define MFMA_Q(QM, QN, BF)                                                    \
  do {                                                                        \
    __builtin_amdgcn_s_setprio(1);                                            \
    _Pragma("unroll") for (int m = 0; m < 4; m++)                             \
        _Pragma("unroll") for (int n = 0; n < 2; n++)                         \
        _Pragma("unroll") for (int kk = 0; kk < 2; kk++)                      \
            acc[QM][QN][m][n] = __builtin_amdgcn_mfma_f32_16x16x32_bf16(      \
                af[m][kk], BF[n][kk], acc[QM][QN][m][n], 0, 0, 0);            \
    __builtin_amdgcn_s_setprio(0);                                            \
  } while (0)

  // prologue: stA(0,0) stB(0,1) stB(0,0) stA(0,1) stA(1,0) stB(1,1)
  load_lds16(pA0, ldA);              load_lds16(pA0h, ldA + 512);
  load_lds16(pB1, ldB + 8192);       load_lds16(pB1h, ldB + 8192 + 512);
  load_lds16(pB0, ldB);              load_lds16(pB0h, ldB + 512);
  load_lds16(pA1, ldA + 8192);       load_lds16(pA1h, ldA + 8192 + 512);
  load_lds16(pA0 + 64, ldA + 16384); load_lds16(pA0h + 64, ldA + 16384 + 512);
  load_lds16(pB1 + 64, ldB + 16384 + 8192);
  load_lds16(pB1h + 64, ldB + 16384 + 8192 + 512);
  asm volatile("s_waitcnt vmcnt(4)\n\ts_barrier" ::: "memory");

  int nt = K >> 6, niter = nt >> 1;
  for (int i = 0; i < niter - 1; i++) {
    rdA(0, 0); rdB(0, 0, bf0);
    load_lds16(pB0 + 64, ldB + 16384);
    load_lds16(pB0h + 64, ldB + 16384 + 512);
    BARL(); MFMA_Q(0, 0, bf0);
    rdB(0, 1, bf1);
    load_lds16(pA1 + 64, ldA + 16384 + 8192);
    load_lds16(pA1h + 64, ldA + 16384 + 8192 + 512);
    BARL(); MFMA_Q(0, 1, bf1);
    rdA(0, 1);
    load_lds16(pA0 + 128, ldA);
    load_lds16(pA0h + 128, ldA + 512);
    BARL(); MFMA_Q(1, 1, bf1);
    load_lds16(pB1 + 128, ldB + 8192);
    load_lds16(pB1h + 128, ldB + 8192 + 512);
    BARL_VM4(); MFMA_Q(1, 0, bf0);
    rdA(1, 0); rdB(1, 0, bf0);
    load_lds16(pB0 + 128, ldB);
    load_lds16(pB0h + 128, ldB + 512);
    BARL(); MFMA_Q(0, 0, bf0);
    rdB(1, 1, bf1);
    load_lds16(pA1 + 128, ldA + 8192);
    load_lds16(pA1h + 128, ldA + 8192 + 512);
    BARL(); MFMA_Q(0, 1, bf1);
    rdA(1, 1);
    load_lds16(pA0 + 192, ldA + 16384);
    load_lds16(pA0h + 192, ldA + 16384 + 512);
    BARL(); MFMA_Q(1, 1, bf1);
    load_lds16(pB1 + 192, ldB + 16384 + 8192);
    load_lds16(pB1h + 192, ldB + 16384 + 8192 + 512);
    BARL_VM4(); MFMA_Q(1, 0, bf0);
    pA0 += 128; pA0h += 128; pA1 += 128; pA1h += 128;
    pB0 += 128; pB0h += 128; pB1 += 128; pB1h += 128;
  }
  // peeled final iteration (verified). Entering outstanding = 4.
  {
    rdA(0, 0); rdB(0, 0, bf0);
    load_lds16(pB0 + 64, ldB + 16384);
    load_lds16(pB0h + 64, ldB + 16384 + 512);
    BARL(); MFMA_Q(0, 0, bf0);
    rdB(0, 1, bf1);
    load_lds16(pA1 + 64, ldA + 16384 + 8192);
    load_lds16(pA1h + 64, ldA + 16384 + 8192 + 512);
    BARL(); MFMA_Q(0, 1, bf1);
    rdA(0, 1);
    BARL(); MFMA_Q(1, 1, bf1);
    BARL_VM0(); MFMA_Q(1, 0, bf0);   // drain + publish all staged LDS
    rdA(1, 0); rdB(1, 0, bf0);
    MFMA_Q(0, 0, bf0);
    rdB(1, 1, bf1);
    MFMA_Q(0, 1, bf1);
    rdA(1, 1);
    MFMA_Q(1, 1, bf1);
    MFMA_Q(1, 0, bf0);
  }
#undef MFMA_Q

  // epilogue: rows fq*4+r, col frow; bf16 rounding via cvt_pk
#pragma unroll
  for (int qm = 0; qm < 2; qm++) {
#pragma unroll
    for (int qn = 0; qn < 2; qn++) {
#pragma unroll
      for (int m = 0; m < 4; m++) {
#pragma unroll
        for (int n = 0; n < 2; n++) {
          f32x4 a4 = acc[qm][qn][m][n];
          int gcol = n0 + qn * 128 + wc * 32 + n * 16 + frow;
#pragma unroll
          for (int rp = 0; rp < 2; rp++) {
            int grow0 = m0 + qm * 128 + wr * 64 + m * 16 + fq * 4 + rp * 2;
            size_t ci0 = (size_t)grow0 * Nc + gcol;
            if (EPI == 0) {
              unsigned pk = cvt_pk_bf16(a4[rp * 2] * scale, a4[rp * 2 + 1] * scale);
              ((u16*)Cout)[(size_t)bz * sC + ci0] = (u16)pk;
              ((u16*)Cout)[(size_t)bz * sC + ci0 + Nc] = (u16)(pk >> 16);
            } else if (EPI == 1) {
              float v0 = aux1[(size_t)bz * sAux1 + ci0];
              float v1 = aux1[(size_t)bz * sAux1 + ci0 + Nc];
              unsigned pk = cvt_pk_bf16(v0 - a4[rp * 2], v1 - a4[rp * 2 + 1]);
              ((u16*)Cout)[(size_t)bz * sC + ci0] = (u16)pk;
              ((u16*)Cout)[(size_t)bz * sC + ci0 + Nc] = (u16)(pk >> 16);
            } else if (EPI == 3) {
              float b2v = aux2[gcol];
              unsigned pk = cvt_pk_bf16(gelu_fast(a4[rp * 2] + b2v),
                                        gelu_fast(a4[rp * 2 + 1] + b2v));
              ((u16*)Cout)[ci0] = (u16)pk;
              ((u16*)Cout)[ci0 + Nc] = (u16)(pk >> 16);
            } else if (EPI == 6) {  // bf16(acc + bias + f32 residual)
              float b2v = aux2[gcol];
              unsigned pk = cvt_pk_bf16(a4[rp * 2] + b2v + aux1[ci0],
                                        a4[rp * 2 + 1] + b2v + aux1[ci0 + Nc]);
              ((u16*)Cout)[ci0] = (u16)pk;
              ((u16*)Cout)[ci0 + Nc] = (u16)(pk >> 16);
            } else {  // EPI == 7: bf16(acc + bias + bf16 residual)
              float b2v = aux2[gcol];
              const u16* r16 = (const u16*)aux1;
              unsigned pk = cvt_pk_bf16(a4[rp * 2] + b2v + bf2f(r16[ci0]),
                                        a4[rp * 2 + 1] + b2v + bf2f(r16[ci0 + Nc]));
              ((u16*)Cout)[ci0] = (u16)pk;
              ((u16*)Cout)[ci0 + Nc] = (u16)(pk >> 16);
            }
          }
        }
      }
    }
  }
}

// ------------------------- launch -------------------------

extern "C" void kernel_launch(void* const* d_in, const int* in_sizes, int n_in,
                              void* d_out, int out_size, void* d_ws, size_t ws_size,
                              hipStream_t stream) {
  const float* q      = (const float*)d_in[0];
  const float* k      = (const float*)d_in[1];
  const float* v      = (const float*)d_in[2];
  const float* W_diff = (const float*)d_in[3];
  const float* b_diff = (const float*)d_in[4];
  const float* ln_g   = (const float*)d_in[5];
  const float* ln_b   = (const float*)d_in[6];
  const float* W1     = (const float*)d_in[7];
  const float* b1     = (const float*)d_in[8];
  const float* W2     = (const float*)d_in[9];
  const float* b2     = (const float*)d_in[10];

  const int B = 8, N = 2048, D = 1024, H = 4096;
  char* ws = (char*)d_ws;
  u16* A    = (u16*)(ws + 0);
  u16* Bm   = (u16*)(ws + 33554432);
  u16* X    = (u16*)(ws + 33554432);   // reuses Bm after GEMM1
  u16* Vt   = (u16*)(ws + 67108864);
  u16* S    = (u16*)(ws + 100663296);
  u16* Hbf  = (u16*)(ws + 134217728);  // LN1 out; reused as bf16 interim by GEMM5
  u16* Wd   = (u16*)(ws + 167772160);
  u16* W1b  = (u16*)(ws + 169869312);
  u16* W2b  = (u16*)(ws + 178257920);
  u16* G    = (u16*)(ws + 0);          // 134M, aliases A/X/Vt/S-low
  u16* Fbf  = (u16*)d_out;             // f_diff bf16 lives in d_out
  float* out = (float*)d_out;

  // fused: weight casts + prob + V^T in one launch (41984 blocks)
  prep_kernel<<<41984, 256, 0, stream>>>(
      W_diff, W1, W2, Wd, W1b, W2b, q, k, A, Bm, v, Vt);

  // GEMM1: S = bf16(-(A @ Bm^T)/32)
  gemm8_kernel<0><<<8 * 8 * 8, 512, 0, stream>>>(
      A, Bm, S, nullptr, nullptr, N, N, D,
      (long)N * D, (long)N * D, (long)N * N, 0, -0.03125f);

  softmax_rows_kernel<<<B * N, 256, 0, stream>>>(S);

  // GEMM2: X = bf16(v - attn @ v)
  gemm8_kernel<1><<<8 * 4 * 8, 512, 0, stream>>>(
      S, Vt, X, v, nullptr, N, D, N,
      (long)N * N, (long)D * N, (long)N * D, (long)N * D, 1.0f);

  // GEMM3: f_diff = bf16(X @ Wd^T + b_diff + q) -> Fbf (in d_out)
  gemm8_kernel<6><<<64 * 4, 512, 0, stream>>>(
      X, Wd, Fbf, q, b_diff, B * N, D, D, 0, 0, 0, 0, 1.0f);

  // h = bf16(LN(f_diff))
  layernorm_rows_kernel<1, 1><<<B * N, 256, 0, stream>>>(Fbf, Hbf, ln_g, ln_b);

  // GEMM4: G = bf16(gelu(h @ W1^T + b1))
  gemm8_kernel<3><<<64 * 16, 512, 0, stream>>>(
      Hbf, W1b, G, nullptr, b1, B * N, H, D, 0, 0, 0, 0, 1.0f);

  // GEMM5: interim = bf16(G @ W2^T + b2 + f_diff) -> Hbf slot (dead after GEMM4)
  gemm8_kernel<7><<<64 * 4, 512, 0, stream>>>(
      G, W2b, Hbf, (const float*)Fbf, b2, B * N, D, H, 0, 0, 0, 0, 1.0f);

  // final LN: bf16 interim -> f32 d_out (overwrites Fbf, which is dead)
  layernorm_rows_kernel<1, 0><<<B * N, 256, 0, stream>>>(Hbf, out, ln_g, ln_b);
}